// Round 1
// baseline (804.358 us; speedup 1.0000x reference)
//
#include <hip/hip_runtime.h>

typedef short v8s __attribute__((ext_vector_type(8)));
typedef short v4s __attribute__((ext_vector_type(4)));
typedef float v4f __attribute__((ext_vector_type(4)));

#define BM 128
#define BN 128
#define BK 64

__device__ __forceinline__ float b2f(unsigned short u) {
    union { unsigned int i; float f; } x; x.i = ((unsigned int)u) << 16; return x.f;
}
__device__ __forceinline__ unsigned short f2b(float f) {
    union { float f; unsigned int i; } x; x.f = f;
    unsigned int r = x.i + 0x7fffu + ((x.i >> 16) & 1u);
    return (unsigned short)(r >> 16);
}

// async global->LDS, 16B per lane. LDS dest is wave-uniform base + lane*16,
// so LDS layout is linear; swizzle is applied on the GLOBAL source address.
__device__ __forceinline__ void gload16(const void* g, void* l) {
    __builtin_amdgcn_global_load_lds(
        (const __attribute__((address_space(1))) void*)g,
        (__attribute__((address_space(3))) void*)l, 16, 0, 0);
}

// Generic MFMA GEMM: C[m,n] = sum_k A[m,k] * BT[n,k]  (+ epilogue). All bf16.
// LDS tiles linear [128][64] (row = 8 chunks of 16B); chunk swizzle c^=(row&7)
// on both the staging source and the ds_read side (involution).
// EPI: 1 transposed bf16 store (batch from gm, 512 rows/batch)
//      2 +bias_f32[gm], bf16 store | 4 +resid_f32[gm*ldr+gn], bf16 store
template<int EPI>
__global__ __launch_bounds__(256)
void gemm_bt(const unsigned short* __restrict__ A, int lda, long aSB,
             const unsigned short* __restrict__ BT, int ldb, long bSB,
             void* __restrict__ C, int ldc, long cSB,
             int K,
             const float* __restrict__ bias,
             const float* __restrict__ resid, int ldr)
{
    const int z = blockIdx.z;

    __shared__ unsigned short As[BM * BK];   // 16 KB
    __shared__ unsigned short Bs[BN * BK];   // 16 KB

    const int tid = threadIdx.x;
    const int wave = tid >> 6, lane = tid & 63;
    const int wm = (wave >> 1) * 64, wn = (wave & 1) * 64;
    const int quad = lane >> 4, l16 = lane & 15;
    const int sx = l16 & 7;
    const int bm = blockIdx.y * BM, bn = blockIdx.x * BN;

    // k0-invariant staging addresses (row, swizzled chunk per thread)
    const unsigned short* aP[4]; const unsigned short* bP[4];
    unsigned short* lA[4]; unsigned short* lB[4];
#pragma unroll
    for (int p = 0; p < 4; p++) {
        int idx = p * 256 + tid;
        int row = idx >> 3, c = idx & 7, cc = c ^ (row & 7);
        aP[p] = A + (long)z * aSB + (long)(bm + row) * lda + cc * 8;
        bP[p] = BT + (long)z * bSB + (long)(bn + row) * ldb + cc * 8;
        lA[p] = &As[idx * 8];
        lB[p] = &Bs[idx * 8];
    }

    v4f acc[4][4] = {};

    for (int k0 = 0; k0 < K; k0 += BK) {
#pragma unroll
        for (int p = 0; p < 4; p++) {
            gload16(aP[p] + k0, lA[p]);
            gload16(bP[p] + k0, lB[p]);
        }
        __syncthreads();   // drains vmcnt for the global_load_lds queue
#pragma unroll
        for (int ks = 0; ks < 2; ks++) {
            v8s af[4], bf[4];
#pragma unroll
            for (int i = 0; i < 4; i++) {
                const int co = ((ks * 4 + quad) ^ sx) * 8;
                af[i] = *(const v8s*)&As[(wm + i * 16 + l16) * 64 + co];
                bf[i] = *(const v8s*)&Bs[(wn + i * 16 + l16) * 64 + co];
            }
#pragma unroll
            for (int i = 0; i < 4; i++)
#pragma unroll
                for (int j = 0; j < 4; j++)
                    acc[i][j] = __builtin_amdgcn_mfma_f32_16x16x32_bf16(af[i], bf[j], acc[i][j], 0, 0, 0);
        }
        __syncthreads();
    }

    unsigned short* Cu = (unsigned short*)C + (long)z * cSB;

#pragma unroll
    for (int i = 0; i < 4; i++) {
        int rowbase = wm + i * 16 + quad * 4;
#pragma unroll
        for (int j = 0; j < 4; j++) {
            int gn = bn + wn + j * 16 + l16;
#pragma unroll
            for (int r = 0; r < 4; r++) {
                int gm = bm + rowbase + r;
                float v = acc[i][j][r];
                if (EPI == 1) {
                    int bb = gm >> 9, mm = gm & 511;
                    ((unsigned short*)C)[(long)bb * cSB + (long)gn * ldc + mm] = f2b(v);
                } else if (EPI == 2) {
                    Cu[(long)gm * ldc + gn] = f2b(v + bias[gm]);
                } else if (EPI == 4) {
                    Cu[(long)gm * ldc + gn] = f2b(v + resid[(long)gm * ldr + gn]);
                }
            }
        }
    }
}

// Fused scores + mask + softmax + attn-write + PV. One block = 128 Q-rows x
// all 512 K-cols for one (b,h). 8 waves x 16 rows.
// QK^T computed with SWAPPED operands: mfma(K,Q) -> D[kcol][qrow], so each
// lane holds ONE q-row (l16) x 128 kcols => softmax is a scalar per-lane
// reduce + shfl_xor(16,32) across quads. P (bf16, normalized) round-trips
// through swizzled LDS (reusing the K tile region) to reach the MFMA
// B-fragment layout for PV; V^T fragments stream from global (L1-resident).
__global__ __launch_bounds__(512)
void scores_pv_k(const unsigned short* __restrict__ q1c,
                 const unsigned short* __restrict__ k1c,
                 const unsigned short* __restrict__ v1t,
                 float* __restrict__ attn,
                 unsigned short* __restrict__ out1,
                 const int* __restrict__ mask1,
                 const int* __restrict__ mask2,
                 float scale)
{
    const int z = blockIdx.z;
    const int b = z >> 3, h = z & 7;
    const unsigned short* Qb = q1c + (long)b * 262144 + h * 64;   // (512 seq, 512 feat)
    const unsigned short* Kb = k1c + (long)b * 262144 + h * 64;
    const unsigned short* Vb = v1t + (long)b * 524288 + (long)h * 128 * 512;  // (128 dv, 512 seq)
    float* Ab = attn + (long)z * 262144;

    // phase 1: K tile [512][64] bf16 in SM[0..32768); phase 2: P [128][512] in SM[0..65536)
    __shared__ unsigned short SM[128 * 512];  // 128 KB
    __shared__ int m2s[512];                  // 2 KB

    const int tid = threadIdx.x;
    const int wave = tid >> 6, lane = tid & 63;
    const int quad = lane >> 4, l16 = lane & 15;
    const int sx = l16 & 7;
    const int bm = blockIdx.x * 128;
    const int row_l = wave * 16 + l16;        // 0..127 (this lane's q-row)

    // stage K via global_load_lds (linear dest, swizzled source chunks)
#pragma unroll
    for (int p = 0; p < 8; p++) {
        int idx = p * 512 + tid;
        int row = idx >> 3, c = idx & 7, cc = c ^ (row & 7);
        gload16(Kb + (long)row * 512 + cc * 8, &SM[idx * 8]);
    }
    m2s[tid] = mask2[b * 512 + tid];
    __syncthreads();

    // Q fragments straight from global (each wave only needs its own 16 rows)
    v8s qf0 = *(const v8s*)&Qb[(long)(bm + row_l) * 512 + quad * 8];
    v8s qf1 = *(const v8s*)&Qb[(long)(bm + row_l) * 512 + 32 + quad * 8];

    v4f acc[32];
#pragma unroll
    for (int j = 0; j < 32; j++) acc[j] = (v4f){0.f, 0.f, 0.f, 0.f};

#pragma unroll
    for (int j = 0; j < 32; j++) {
        const unsigned short* kb_ = &SM[(j * 16 + l16) * 64];
        v8s af0 = *(const v8s*)&kb_[(quad ^ sx) * 8];
        v8s af1 = *(const v8s*)&kb_[((4 + quad) ^ sx) * 8];
        acc[j] = __builtin_amdgcn_mfma_f32_16x16x32_bf16(af0, qf0, acc[j], 0, 0, 0);
        acc[j] = __builtin_amdgcn_mfma_f32_16x16x32_bf16(af1, qf1, acc[j], 0, 0, 0);
    }
    // acc[j][r] = S[qrow = bm+row_l][kcol = j*16 + quad*4 + r]

    const int m1 = mask1[b * 512 + bm + row_l];
    float mx = -1e30f;
#pragma unroll
    for (int j = 0; j < 32; j++) {
        union { int4 v; int a[4]; } m2u;
        m2u.v = *(const int4*)&m2s[j * 16 + quad * 4];
#pragma unroll
        for (int r = 0; r < 4; r++) {
            float s = acc[j][r] * scale;
            if (m1 != 0 || m2u.a[r] != 0) s = 1e-9f;
            acc[j][r] = s;
            mx = fmaxf(mx, s);
        }
    }
    mx = fmaxf(mx, __shfl_xor(mx, 16, 64));
    mx = fmaxf(mx, __shfl_xor(mx, 32, 64));

    float sum = 0.f;
#pragma unroll
    for (int j = 0; j < 32; j++)
#pragma unroll
        for (int r = 0; r < 4; r++) {
            float e = __expf(acc[j][r] - mx);
            acc[j][r] = e;
            sum += e;
        }
    sum += __shfl_xor(sum, 16, 64);
    sum += __shfl_xor(sum, 32, 64);
    const float inv = 1.0f / sum;

    __syncthreads();   // all K reads done; SM region becomes P

    // write attn f32 (required output) + P bf16 into swizzled LDS.
    // slot s (16B = 8 kcols) stored at s ^ (row&7); row&7 == l16&7 here.
    float* Arow = Ab + (long)(bm + row_l) * 512;
    unsigned short* Prow = &SM[row_l * 512];
#pragma unroll
    for (int j = 0; j < 32; j++) {
        float4 wv;
        wv.x = acc[j][0] * inv; wv.y = acc[j][1] * inv;
        wv.z = acc[j][2] * inv; wv.w = acc[j][3] * inv;
        *(float4*)&Arow[j * 16 + quad * 4] = wv;
        unsigned int lo = (unsigned int)f2b(wv.x) | ((unsigned int)f2b(wv.y) << 16);
        unsigned int hi = (unsigned int)f2b(wv.z) | ((unsigned int)f2b(wv.w) << 16);
        int s = 2 * j + (quad >> 1);
        uint2 u; u.x = lo; u.y = hi;
        *(uint2*)&Prow[((s ^ sx) << 3) + ((quad & 1) << 2)] = u;
    }

    // PV: out^T[dv][qrow] = sum_k V^T[dv][k] * P[qrow][k]
    v4f acc2[8];
#pragma unroll
    for (int t = 0; t < 8; t++) acc2[t] = (v4f){0.f, 0.f, 0.f, 0.f};

#pragma unroll 2
    for (int kt = 0; kt < 16; kt++) {
        v8s pf = *(const v8s*)&Prow[(((4 * kt + quad) ^ sx) << 3)];
        v8s vf[8];
#pragma unroll
        for (int t = 0; t < 8; t++)
            vf[t] = *(const v8s*)&Vb[(long)(t * 16 + l16) * 512 + kt * 32 + quad * 8];
#pragma unroll
        for (int t = 0; t < 8; t++)
            acc2[t] = __builtin_amdgcn_mfma_f32_16x16x32_bf16(vf[t], pf, acc2[t], 0, 0, 0);
    }

    // out1[b][qrow][h*128 + dv], dv = t*16 + quad*4 + r
    unsigned short* Orow = out1 + (long)b * 524288 + (long)(bm + row_l) * 1024 + h * 128;
#pragma unroll
    for (int t = 0; t < 8; t++) {
        v4s o;
        o[0] = (short)f2b(acc2[t][0]); o[1] = (short)f2b(acc2[t][1]);
        o[2] = (short)f2b(acc2[t][2]); o[3] = (short)f2b(acc2[t][3]);
        *(v4s*)&Orow[t * 16 + quad * 4] = o;
    }
}

// all weight prep (4 transposes f32->bf16^T + Wconv cast) + q/k/v bf16 casts
__global__ __launch_bounds__(256)
void prep_k(const float* __restrict__ Wq, const float* __restrict__ Wk,
            const float* __restrict__ Wv, const float* __restrict__ Wfc,
            const float* __restrict__ Wconv,
            const float* __restrict__ qf, const float* __restrict__ kf,
            const float* __restrict__ vf,
            unsigned short* __restrict__ WqT, unsigned short* __restrict__ WkT,
            unsigned short* __restrict__ WvT, unsigned short* __restrict__ WfcT,
            unsigned short* __restrict__ Wconv_b,
            unsigned short* __restrict__ qb, unsigned short* __restrict__ kb,
            unsigned short* __restrict__ vb)
{
    __shared__ float t[32][33];
    int blk = blockIdx.x, tid = threadIdx.x;
    if (blk < 2304) {
        const float* src; unsigned short* dst; int K, N, local;
        if (blk < 384)       { src = Wq;  dst = WqT;  K = 768;  N = 512;  local = blk; }
        else if (blk < 768)  { src = Wk;  dst = WkT;  K = 768;  N = 512;  local = blk - 384; }
        else if (blk < 1536) { src = Wv;  dst = WvT;  K = 768;  N = 1024; local = blk - 768; }
        else                 { src = Wfc; dst = WfcT; K = 1024; N = 768;  local = blk - 1536; }
        int nb32 = N >> 5;
        int kb32 = (local / nb32) * 32, nb = (local % nb32) * 32;
        int tx = tid & 31, ty = tid >> 5;
#pragma unroll
        for (int i = 0; i < 32; i += 8)
            t[ty + i][tx] = src[(long)(kb32 + ty + i) * N + nb + tx];
        __syncthreads();
#pragma unroll
        for (int i = 0; i < 32; i += 8)
            dst[(long)(nb + ty + i) * K + kb32 + tx] = f2b(t[tx][ty + i]);
    } else if (blk < 3328) {
        int i = (blk - 2304) * 256 + tid;   // Wconv: 512*512 = 262144
        Wconv_b[i] = f2b(Wconv[i]);
    } else {
        long t0 = (long)(blk - 3328) * 4096 + (long)tid * 16;
        const float* src; unsigned short* dst; long i = t0;
        if (t0 < 12582912L)       { src = qf; dst = qb; }
        else if (t0 < 25165824L)  { src = kf; dst = kb; i = t0 - 12582912L; }
        else                      { src = vf; dst = vb; i = t0 - 25165824L; }
        float4 a = *(const float4*)&src[i];
        float4 b4 = *(const float4*)&src[i + 4];
        float4 c4 = *(const float4*)&src[i + 8];
        float4 d4 = *(const float4*)&src[i + 12];
        v8s r0, r1;
        r0[0] = (short)f2b(a.x);  r0[1] = (short)f2b(a.y);
        r0[2] = (short)f2b(a.z);  r0[3] = (short)f2b(a.w);
        r0[4] = (short)f2b(b4.x); r0[5] = (short)f2b(b4.y);
        r0[6] = (short)f2b(b4.z); r0[7] = (short)f2b(b4.w);
        r1[0] = (short)f2b(c4.x); r1[1] = (short)f2b(c4.y);
        r1[2] = (short)f2b(c4.z); r1[3] = (short)f2b(c4.w);
        r1[4] = (short)f2b(d4.x); r1[5] = (short)f2b(d4.y);
        r1[6] = (short)f2b(d4.z); r1[7] = (short)f2b(d4.w);
        *(v8s*)&dst[i] = r0;
        *(v8s*)&dst[i + 8] = r1;
    }
}

// LayerNorm over rows of 768 (bf16 in, f32 gamma/beta, f32 out) + nan->0
__global__ __launch_bounds__(256)
void ln_k(const unsigned short* __restrict__ x,
          const float* __restrict__ gamma,
          const float* __restrict__ beta,
          float* __restrict__ out)
{
    long row = (long)blockIdx.x * 4 + (threadIdx.x >> 6);
    int lane = threadIdx.x & 63;
    const unsigned short* p = x + row * 768;
    v8s a = *(const v8s*)&p[lane * 8];          // cols lane*8 .. +7
    v4s b4 = *(const v4s*)&p[512 + lane * 4];   // cols 512+lane*4 .. +3
    float v[12];
    float s = 0.f, s2 = 0.f;
#pragma unroll
    for (int j = 0; j < 8; j++) { v[j] = b2f((unsigned short)a[j]); s += v[j]; s2 += v[j] * v[j]; }
#pragma unroll
    for (int j = 0; j < 4; j++) { v[8 + j] = b2f((unsigned short)b4[j]); s += v[8 + j]; s2 += v[8 + j] * v[8 + j]; }
#pragma unroll
    for (int o = 32; o > 0; o >>= 1) { s += __shfl_xor(s, o, 64); s2 += __shfl_xor(s2, o, 64); }
    float mean = s * (1.0f / 768.0f);
    float var = s2 * (1.0f / 768.0f) - mean * mean;
    if (!(var >= 0.f)) var = 0.f;
    float rstd = rsqrtf(var + 1e-6f);
    float o12[12];
#pragma unroll
    for (int j = 0; j < 8; j++) {
        int c = lane * 8 + j;
        float o = (v[j] - mean) * rstd * gamma[c] + beta[c];
        union { float f; unsigned int i; } u; u.f = o;
        if ((u.i & 0x7FFFFFFFu) > 0x7F800000u) u.f = 0.f;
        o12[j] = u.f;
    }
#pragma unroll
    for (int j = 0; j < 4; j++) {
        int c = 512 + lane * 4 + j;
        float o = (v[8 + j] - mean) * rstd * gamma[c] + beta[c];
        union { float f; unsigned int i; } u; u.f = o;
        if ((u.i & 0x7FFFFFFFu) > 0x7F800000u) u.f = 0.f;
        o12[8 + j] = u.f;
    }
    float4 f0; f0.x = o12[0]; f0.y = o12[1]; f0.z = o12[2]; f0.w = o12[3];
    float4 f1; f1.x = o12[4]; f1.y = o12[5]; f1.z = o12[6]; f1.w = o12[7];
    float4 f2; f2.x = o12[8]; f2.y = o12[9]; f2.z = o12[10]; f2.w = o12[11];
    *(float4*)&out[row * 768 + lane * 8] = f0;
    *(float4*)&out[row * 768 + lane * 8 + 4] = f1;
    *(float4*)&out[row * 768 + 512 + lane * 4] = f2;
}

extern "C" void kernel_launch(void* const* d_in, const int* in_sizes, int n_in,
                              void* d_out, int out_size, void* d_ws, size_t ws_size,
                              hipStream_t stream)
{
    // B=32, L=512, D_EMB=768, D_K=512, D_V=1024, H=8 — all I/O float32
    const float* q     = (const float*)d_in[0];
    const float* k     = (const float*)d_in[1];
    const float* v     = (const float*)d_in[2];
    const float* Wq    = (const float*)d_in[3];
    const float* Wk    = (const float*)d_in[4];
    const float* Wv    = (const float*)d_in[5];
    const float* Wconv = (const float*)d_in[6];
    const float* bconv = (const float*)d_in[7];
    const float* Wfc   = (const float*)d_in[8];
    const float* gamma = (const float*)d_in[9];
    const float* beta  = (const float*)d_in[10];
    const int* mask1   = (const int*)d_in[11];
    const int* mask2   = (const int*)d_in[12];

    float* out  = (float*)d_out;               // (32,512,768) f32
    float* attn = out + 12582912;              // (32,8,512,512) f32

    // ws layout (ushort elems), peak 36,175,872 = 72.4 MB (unchanged)
    unsigned short* ws = (unsigned short*)d_ws;
    unsigned short* WqT     = ws;              // 512x768
    unsigned short* WkT     = ws + 393216;     // 512x768
    unsigned short* WvT     = ws + 786432;     // 1024x768
    unsigned short* WfcT    = ws + 1572864;    // 768x1024
    unsigned short* Wconv_b = ws + 2359296;    // 512x512
    unsigned short* q1c     = ws + 2621440;    // (32,512,512)
    unsigned short* k1c     = ws + 11010048;   // (32,512,512)
    unsigned short* v1t     = ws + 19398656;   // (32,1024,512)  [.. 36175872)
    unsigned short* out2    = ws + 19398656;   // (32,512,768)  aliases v1t (dead after scores_pv)

    // scratch in d_out's attn region (268 MB f32) — all dead before scores_pv writes attn
    unsigned short* q1t = (unsigned short*)attn;             // (32,512,512) feature-major
    unsigned short* k1t = q1t + 8388608;                     // (32,512,512)
    unsigned short* qb  = q1t + 16777216;                    // (32,512,768) bf16 cast of q
    unsigned short* kb  = q1t + 29360128;                    // bf16 cast of k
    unsigned short* vb  = q1t + 41943040;                    // bf16 cast of v  [.. 54525952)
    // out1 in d_out's "out" region (50.3 MB f32 >= 33.5 MB bf16); consumed by FC
    // before ln_k overwrites the region with the final f32 output.
    unsigned short* out1 = (unsigned short*)out;             // (32,512,1024) bf16

    // all weight prep + q/k/v bf16 casts in one dispatch
    prep_k<<<12544, 256, 0, stream>>>(Wq, Wk, Wv, Wfc, Wconv, q, k, v,
                                      WqT, WkT, WvT, WfcT, Wconv_b, qb, kb, vb);

    const float scale = 0.04419417382415922f;  // 1/sqrt(512)

    // projections (all bf16), transposed per-batch store (feature-major)
    gemm_bt<1><<<dim3(4, 128, 1), 256, 0, stream>>>(
        qb, 768, 0, WqT, 768, 0, q1t, 512, 262144, 768, nullptr, nullptr, 0);
    gemm_bt<1><<<dim3(4, 128, 1), 256, 0, stream>>>(
        kb, 768, 0, WkT, 768, 0, k1t, 512, 262144, 768, nullptr, nullptr, 0);
    gemm_bt<1><<<dim3(8, 128, 1), 256, 0, stream>>>(
        vb, 768, 0, WvT, 768, 0, v1t, 512, 524288, 768, nullptr, nullptr, 0);

    // conv over seq axis: q1c[b] = Wconv_b (o x c) x q1t[b]^T + bconv
    gemm_bt<2><<<dim3(4, 4, 32), 256, 0, stream>>>(
        Wconv_b, 512, 0, q1t, 512, 262144, q1c, 512, 262144, 512, bconv, nullptr, 0);
    gemm_bt<2><<<dim3(4, 4, 32), 256, 0, stream>>>(
        Wconv_b, 512, 0, k1t, 512, 262144, k1c, 512, 262144, 512, bconv, nullptr, 0);

    // fused scores + mask + softmax + attn write + PV -> out1 bf16
    scores_pv_k<<<dim3(4, 1, 256), 512, 0, stream>>>(
        q1c, k1c, v1t, attn, out1, mask1, mask2, scale);

    // FC + f32 residual
    gemm_bt<4><<<dim3(6, 128, 1), 256, 0, stream>>>(
        out1, 1024, 0, WfcT, 1024, 0, out2, 768, 0, 1024, nullptr, q, 768);

    // LayerNorm + nan->0 -> f32 d_out
    ln_k<<<4096, 256, 0, stream>>>(out2, gamma, beta, out);
}